// Round 1
// baseline (456.807 us; speedup 1.0000x reference)
//
#include <hip/hip_runtime.h>

#define N_POINTS   2000000
#define NUM_GRAPHS 16384
#define HID        40
#define SLOPE      0.01f

__device__ __forceinline__ float lrelu(float v) { return v > 0.f ? v : SLOPE * v; }

// ---------------- Pass A: emb FFN + segment-sum xe[5] -> x_aggr [B,5] ----------------
__global__ __launch_bounds__(256) void k_emb_aggr(
    const float* __restrict__ x, const int* __restrict__ batch,
    const float* __restrict__ We1, const float* __restrict__ We2,
    float* __restrict__ x_aggr)
{
    __shared__ float sWe1[3 * HID];   // [3][40]
    __shared__ float sWe2[HID * 5];   // [40][5]
    for (int k = threadIdx.x; k < 3 * HID; k += 256) sWe1[k] = We1[k];
    for (int k = threadIdx.x; k < HID * 5; k += 256) sWe2[k] = We2[k];
    __syncthreads();

    int i = blockIdx.x * 256 + threadIdx.x;
    bool valid = i < N_POINTS;
    int ic = valid ? i : (N_POINTS - 1);
    float x0 = x[ic * 3 + 0], x1 = x[ic * 3 + 1], x2 = x[ic * 3 + 2];
    int b = valid ? batch[ic] : -1;

    float h[HID];
#pragma unroll
    for (int j = 0; j < HID; ++j)
        h[j] = lrelu(x0 * sWe1[j] + x1 * sWe1[HID + j] + x2 * sWe1[2 * HID + j]);

    float xe[5];
#pragma unroll
    for (int c = 0; c < 5; ++c) {
        float s = 0.f;
#pragma unroll
        for (int j = 0; j < HID; ++j) s += h[j] * sWe2[j * 5 + c];
        xe[c] = valid ? lrelu(s) : 0.f;
    }

    // wave segmented inclusive scan (batch sorted -> runs within wave)
    int lane = threadIdx.x & 63;
#pragma unroll
    for (int d = 1; d < 64; d <<= 1) {
        int bo = __shfl_up(b, d);
        bool ok = (lane >= d) && (bo == b);
#pragma unroll
        for (int c = 0; c < 5; ++c) {
            float vo = __shfl_up(xe[c], d);
            if (ok) xe[c] += vo;
        }
    }
    int bn = __shfl_down(b, 1);
    bool lastl = (lane == 63) || (bn != b);
    if (lastl && b >= 0) {
#pragma unroll
        for (int c = 0; c < 5; ++c) atomicAdd(&x_aggr[b * 5 + c], xe[c]);
    }
}

// ---------------- Pass B: per-graph global FFN + fold into W_out1 rows 5..8 ----------------
// g_contrib[b][j] = sum_c lrelu-ffn(x_aggr)[c] * W_out1[5+c][j]
__global__ __launch_bounds__(256) void k_global(
    const float* __restrict__ x_aggr,
    const float* __restrict__ Wg1, const float* __restrict__ Wg2,
    const float* __restrict__ Wo1,          // full [9][40]
    float* __restrict__ g_contrib)
{
    __shared__ float sWg1[5 * HID];   // [5][40]
    __shared__ float sWg2[HID * 4];   // [40][4]
    __shared__ float sWo1g[4 * HID];  // rows 5..8 of W_out1
    for (int k = threadIdx.x; k < 5 * HID; k += 256) sWg1[k] = Wg1[k];
    for (int k = threadIdx.x; k < HID * 4; k += 256) sWg2[k] = Wg2[k];
    for (int k = threadIdx.x; k < 4 * HID; k += 256) sWo1g[k] = Wo1[5 * HID + k];
    __syncthreads();

    int bg = blockIdx.x * 256 + threadIdx.x;
    if (bg >= NUM_GRAPHS) return;

    float a[5];
#pragma unroll
    for (int c = 0; c < 5; ++c) a[c] = x_aggr[bg * 5 + c];

    float h[HID];
#pragma unroll
    for (int j = 0; j < HID; ++j) {
        float s = 0.f;
#pragma unroll
        for (int c = 0; c < 5; ++c) s += a[c] * sWg1[c * HID + j];
        h[j] = lrelu(s);
    }
    float g[4];
#pragma unroll
    for (int c = 0; c < 4; ++c) {
        float s = 0.f;
#pragma unroll
        for (int j = 0; j < HID; ++j) s += h[j] * sWg2[j * 4 + c];
        g[c] = lrelu(s);
    }
#pragma unroll
    for (int j = 0; j < HID; ++j) {
        float s = 0.f;
#pragma unroll
        for (int c = 0; c < 4; ++c) s += g[c] * sWo1g[c * HID + j];
        g_contrib[bg * HID + j] = s;
    }
}

// ---------------- Pass C: recompute emb, out FFN, segment-sum xo[32] -> pooled ----------------
__global__ __launch_bounds__(256) void k_out_pool(
    const float* __restrict__ x, const int* __restrict__ batch,
    const float* __restrict__ We1, const float* __restrict__ We2,
    const float* __restrict__ Wo1, const float* __restrict__ Wo2,
    const float* __restrict__ g_contrib,
    float* __restrict__ pooled)
{
    __shared__ float sWe1[3 * HID];
    __shared__ float sWe2[HID * 5];
    __shared__ float sWo1[5 * HID];    // rows 0..4
    __shared__ float sWo2[HID * 32];   // [40][32]
    for (int k = threadIdx.x; k < 3 * HID; k += 256) sWe1[k] = We1[k];
    for (int k = threadIdx.x; k < HID * 5; k += 256) sWe2[k] = We2[k];
    for (int k = threadIdx.x; k < 5 * HID; k += 256) sWo1[k] = Wo1[k];
    for (int k = threadIdx.x; k < HID * 32; k += 256) sWo2[k] = Wo2[k];
    __syncthreads();

    int i = blockIdx.x * 256 + threadIdx.x;
    bool valid = i < N_POINTS;
    int ic = valid ? i : (N_POINTS - 1);
    float x0 = x[ic * 3 + 0], x1 = x[ic * 3 + 1], x2 = x[ic * 3 + 2];
    int b = valid ? batch[ic] : -1;
    int bgc = valid ? b : 0;

    float h[HID];
#pragma unroll
    for (int j = 0; j < HID; ++j)
        h[j] = lrelu(x0 * sWe1[j] + x1 * sWe1[HID + j] + x2 * sWe1[2 * HID + j]);

    float xe[5];
#pragma unroll
    for (int c = 0; c < 5; ++c) {
        float s = 0.f;
#pragma unroll
        for (int j = 0; j < HID; ++j) s += h[j] * sWe2[j * 5 + c];
        xe[c] = lrelu(s);
    }

    // h1 = lrelu(xe @ Wo1[0:5] + g_contrib[b])  (reuse h[])
    const float* gc = g_contrib + (size_t)bgc * HID;
#pragma unroll
    for (int j = 0; j < HID; ++j) {
        float s = gc[j];
#pragma unroll
        for (int c = 0; c < 5; ++c) s += xe[c] * sWo1[c * HID + j];
        h[j] = lrelu(s);
    }

    // segmented-scan masks (shared across all 32 components)
    int lane = threadIdx.x & 63;
    bool ok[6];
#pragma unroll
    for (int s6 = 0; s6 < 6; ++s6) {
        int d = 1 << s6;
        int bo = __shfl_up(b, d);
        ok[s6] = (lane >= d) && (bo == b);
    }
    int bn = __shfl_down(b, 1);
    bool lastl = (lane == 63) || (bn != b);

#pragma unroll
    for (int c = 0; c < 32; ++c) {
        float s = 0.f;
#pragma unroll
        for (int j = 0; j < HID; ++j) s += h[j] * sWo2[j * 32 + c];
        s = valid ? lrelu(s) : 0.f;
#pragma unroll
        for (int s6 = 0; s6 < 6; ++s6) {
            float so = __shfl_up(s, 1 << s6);
            if (ok[s6]) s += so;
        }
        if (lastl && b >= 0) atomicAdd(&pooled[b * 32 + c], s);
    }
}

// ---------------- Pass D: disc head per graph ----------------
__global__ __launch_bounds__(256) void k_disc(
    const float* __restrict__ pooled,
    const float* __restrict__ Wd1, const float* __restrict__ Wd2,
    float* __restrict__ out)
{
    __shared__ float sWd1[32 * HID];  // [32][40]
    __shared__ float sWd2[HID];       // [40][1]
    for (int k = threadIdx.x; k < 32 * HID; k += 256) sWd1[k] = Wd1[k];
    for (int k = threadIdx.x; k < HID; k += 256) sWd2[k] = Wd2[k];
    __syncthreads();

    int bg = blockIdx.x * 256 + threadIdx.x;
    if (bg >= NUM_GRAPHS) return;

    float p[32];
#pragma unroll
    for (int c = 0; c < 32; ++c) p[c] = pooled[bg * 32 + c];

    float acc = 0.f;
#pragma unroll
    for (int j = 0; j < HID; ++j) {
        float s = 0.f;
#pragma unroll
        for (int c = 0; c < 32; ++c) s += p[c] * sWd1[c * HID + j];
        acc += lrelu(s) * sWd2[j];
    }
    out[bg] = acc;
}

extern "C" void kernel_launch(void* const* d_in, const int* in_sizes, int n_in,
                              void* d_out, int out_size, void* d_ws, size_t ws_size,
                              hipStream_t stream) {
    const float* x     = (const float*)d_in[0];
    const int*   batch = (const int*)  d_in[1];
    const float* We1   = (const float*)d_in[2];
    const float* We2   = (const float*)d_in[3];
    const float* Wg1   = (const float*)d_in[4];
    const float* Wg2   = (const float*)d_in[5];
    const float* Wo1   = (const float*)d_in[6];
    const float* Wo2   = (const float*)d_in[7];
    const float* Wd1   = (const float*)d_in[8];
    const float* Wd2   = (const float*)d_in[9];
    float* out = (float*)d_out;

    // workspace layout: [x_aggr B*5][pooled B*32][g_contrib B*40]
    float* x_aggr    = (float*)d_ws;
    float* pooled    = x_aggr + NUM_GRAPHS * 5;
    float* g_contrib = pooled + NUM_GRAPHS * 32;

    // zero the atomic accumulators (ws is poisoned to 0xAA before every launch)
    hipMemsetAsync(d_ws, 0, (size_t)NUM_GRAPHS * (5 + 32) * sizeof(float), stream);

    int nblk = (N_POINTS + 255) / 256;
    int gblk = (NUM_GRAPHS + 255) / 256;
    k_emb_aggr<<<nblk, 256, 0, stream>>>(x, batch, We1, We2, x_aggr);
    k_global <<<gblk, 256, 0, stream>>>(x_aggr, Wg1, Wg2, Wo1, g_contrib);
    k_out_pool<<<nblk, 256, 0, stream>>>(x, batch, We1, We2, Wo1, Wo2, g_contrib, pooled);
    k_disc   <<<gblk, 256, 0, stream>>>(pooled, Wd1, Wd2, out);
}